// Round 7
// baseline (2877.710 us; speedup 1.0000x reference)
//
#include <hip/hip_runtime.h>
#include <hip/hip_bf16.h>
#include <math.h>
#include <stdio.h>

typedef long long ll;
typedef __bf16 bf16x8 __attribute__((ext_vector_type(8)));
typedef float f32x4 __attribute__((ext_vector_type(4)));

#define CIN    2
#define COUTC  2
#define Hh     180
#define Ww     360
#define Ech    256
#define NLAYERS 4
#define LMAX   90
#define MMAX   91
#define HIDD   512
#define NPIX   (Hh*Ww)       // 64800
#define CHROWS (Ech*Hh)      // 46080
#define S2     (2*MMAX)      // 182
#define CDIV(a,b) (((a)+(b)-1)/(b))

// ================= bf16 MFMA GEMM, 2-phase double-buffered =================
// C[z,i,j] = sum_k A[z,i,k]*B[z,j,k]   (B supplied transposed: [N][K])
// K multiple of 32. ldA/ldB multiples of 8. Edges on M,N guarded.
struct GemmBP {
    const __hip_bfloat16* A; const __hip_bfloat16* B;
    const float* Dd; void* C;
    ll sAb; int ldA;
    ll sBb; int ldB;
    ll sCb, sCi, sCj;
    ll sDb, sDi, sDj;
    int M, N, K;
    int epi;   // bit0: +Dd, bit1: gelu, bit2: store bf16
};

__device__ __forceinline__ void glds16(const __hip_bfloat16* g, __hip_bfloat16* l) {
    __builtin_amdgcn_global_load_lds(
        (const __attribute__((address_space(1))) unsigned int*)g,
        (__attribute__((address_space(3))) unsigned int*)l,
        16, 0, 0);
}

__global__ __launch_bounds__(256)
void gemm_bf(GemmBP p) {
    // LDS: double-buffered [kg(4)][row(128)][8] tiles for A and B (2 x 16KB)
    __shared__ __hip_bfloat16 As[2][4096];
    __shared__ __hip_bfloat16 Bs[2][4096];
    const int t = threadIdx.x;
    const int lane = t & 63, wv = t >> 6;
    const int wr = wv >> 1, wc = wv & 1;
    const int z = blockIdx.z;
    const int i0 = blockIdx.y * 128, j0 = blockIdx.x * 128;

    // staging role per wave: w0: A kg0-1, w1: A kg2-3, w2: B kg0-1, w3: B kg2-3
    const bool isB = (wv >= 2);
    const int kgbase = (wv & 1) * 2;
    const __hip_bfloat16* Gp = isB ? (p.B + (ll)z * p.sBb) : (p.A + (ll)z * p.sAb);
    const int ld  = isB ? p.ldB : p.ldA;
    const int lim = isB ? p.N : p.M;
    const int rb0 = isB ? j0 : i0;

    // hoisted per-thread staging addresses (only +kt varies inside the loop)
    const __hip_bfloat16* gptr[4];
    int ldoff[4];
    bool ok[4];
#pragma unroll
    for (int s = 0; s < 4; ++s) {
        int kg = kgbase + (s >> 1), half = s & 1;
        int grow = rb0 + half * 64 + lane;
        gptr[s] = Gp + (ll)grow * ld + kg * 8;
        ldoff[s] = kg * 1024 + half * 512;     // wave-uniform LDS base (+lane*8 implicit)
        ok[s] = (grow < lim);
    }

    f32x4 acc[4][4] = {};

    auto stage = [&](int buf, int kt) {
        __hip_bfloat16* Ls = (isB ? Bs[buf] : As[buf]);
#pragma unroll
        for (int s = 0; s < 4; ++s)
            if (ok[s]) glds16(gptr[s] + kt, Ls + ldoff[s]);
    };
    auto compute = [&](int buf) {
        bf16x8 af[4], bg[4];
#pragma unroll
        for (int f = 0; f < 4; ++f) {
            af[f] = *(const bf16x8*)(As[buf] + (lane >> 4) * 1024 + (wr * 64 + f * 16 + (lane & 15)) * 8);
            bg[f] = *(const bf16x8*)(Bs[buf] + (lane >> 4) * 1024 + (wc * 64 + f * 16 + (lane & 15)) * 8);
        }
#pragma unroll
        for (int fr = 0; fr < 4; ++fr)
#pragma unroll
            for (int fn = 0; fn < 4; ++fn)
                acc[fr][fn] = __builtin_amdgcn_mfma_f32_16x16x32_bf16(af[fr], bg[fn], acc[fr][fn], 0, 0, 0);
    };

    // prologue: stage tile 0 into buffer 0; single vmcnt-drain barrier
    stage(0, 0);
    __syncthreads();

    int cur = 0;
    for (int kt = 32; kt < p.K; kt += 32) {
        stage(cur ^ 1, kt);     // issue next-tile loads FIRST (latency hides under MFMA)
        compute(cur);           // ds_read + MFMA from current buffer
        __syncthreads();        // one vmcnt(0)+barrier per K-step
        cur ^= 1;
    }
    compute(cur);               // epilogue: last tile (no prefetch)

    float* Cf = (float*)p.C;
    __hip_bfloat16* Ch = (__hip_bfloat16*)p.C;
    const float* Db = p.Dd ? (p.Dd + (ll)z * p.sDb) : nullptr;
    const ll cb = (ll)z * p.sCb;
#pragma unroll
    for (int fr = 0; fr < 4; ++fr) {
#pragma unroll
        for (int j = 0; j < 4; ++j) {
            int row = i0 + wr * 64 + fr * 16 + (lane >> 4) * 4 + j;
            if (row >= p.M) continue;
#pragma unroll
            for (int fn = 0; fn < 4; ++fn) {
                int col = j0 + wc * 64 + fn * 16 + (lane & 15);
                if (col >= p.N) continue;
                float r = acc[fr][fn][j];
                if (p.epi & 1) r += Db[(ll)row * p.sDi + (ll)col * p.sDj];
                if (p.epi & 2) r = 0.5f * r * (1.0f + erff(r * 0.70710678118654752f));
                ll ca = cb + (ll)row * p.sCi + (ll)col * p.sCj;
                if (p.epi & 4) Ch[ca] = __hip_bfloat16(r);
                else           Cf[ca] = r;
            }
        }
    }
}

// ================= fp32 GEMM (K=2 encoder/decoder paths) =================
struct GemmP {
    const float* A; const float* Bm; const float* Dd; float* C;
    ll sAb, sAi, sAk;
    ll sBb, sBk, sBj;
    ll sCb, sCi, sCj;
    ll sDb, sDi, sDj;
    int M, N, K;
    float alpha;
    int epi;
};

#define BM 64
#define BN 64
#define BK 16

__global__ __launch_bounds__(256)
void gemm_f32(GemmP p) {
    __shared__ float As[BM][BK];
    __shared__ float Bs[BK][BN];
    const int t  = threadIdx.x;
    const int tx = t & 15, ty = t >> 4;
    const int z  = blockIdx.z;
    const int i0 = blockIdx.y * BM;
    const int j0 = blockIdx.x * BN;
    const float* Ab = p.A  + (ll)z * p.sAb;
    const float* Bb = p.Bm + (ll)z * p.sBb;
    float acc[4][4] = {};
    for (int kt = 0; kt < p.K; kt += BK) {
#pragma unroll
        for (int s = 0; s < 4; ++s) {
            int idx = t + 256 * s;
            int i = idx >> 4, k = idx & 15;
            int gi = i0 + i, gk = kt + k;
            As[i][k] = (gi < p.M && gk < p.K) ? Ab[(ll)gi * p.sAi + (ll)gk * p.sAk] : 0.0f;
        }
#pragma unroll
        for (int s = 0; s < 4; ++s) {
            int idx = t + 256 * s;
            int k = idx >> 6, j = idx & 63;
            int gk = kt + k, gj = j0 + j;
            Bs[k][j] = (gk < p.K && gj < p.N) ? Bb[(ll)gk * p.sBk + (ll)gj * p.sBj] : 0.0f;
        }
        __syncthreads();
#pragma unroll
        for (int kk = 0; kk < BK; ++kk) {
            float a[4], b[4];
#pragma unroll
            for (int ii = 0; ii < 4; ++ii) a[ii] = As[ty + 16*ii][kk];
#pragma unroll
            for (int jj = 0; jj < 4; ++jj) b[jj] = Bs[kk][tx + 16*jj];
#pragma unroll
            for (int ii = 0; ii < 4; ++ii)
#pragma unroll
                for (int jj = 0; jj < 4; ++jj)
                    acc[ii][jj] += a[ii] * b[jj];
        }
        __syncthreads();
    }
    float* Cb = p.C + (ll)z * p.sCb;
    const float* Db = p.Dd ? (p.Dd + (ll)z * p.sDb) : nullptr;
#pragma unroll
    for (int ii = 0; ii < 4; ++ii) {
        int gi = i0 + ty + 16*ii;
        if (gi >= p.M) continue;
#pragma unroll
        for (int jj = 0; jj < 4; ++jj) {
            int gj = j0 + tx + 16*jj;
            if (gj >= p.N) continue;
            float r = p.alpha * acc[ii][jj];
            if (p.epi & 1) r += Db[(ll)gi * p.sDi + (ll)gj * p.sDj];
            if (p.epi & 2) r = 0.5f * r * (1.0f + erff(r * 0.70710678118654752f));
            Cb[(ll)gi * p.sCi + (ll)gj * p.sCj] = r;
        }
    }
}

// ================= transpose + fp32->bf16 convert (with sign) =================
__global__ __launch_bounds__(256)
void transp_cv(const float* __restrict__ src, __hip_bfloat16* __restrict__ dst, int R, int C,
               ll srcB, ll srcR, ll dstB, ll dstR, float sign) {
    __shared__ float tile[32][33];
    ll b = blockIdx.z;
    int r0 = blockIdx.y * 32, c0 = blockIdx.x * 32;
    const float* s = src + b * srcB;
    __hip_bfloat16* d = dst + b * dstB;
    int tx = threadIdx.x, ty = threadIdx.y;   // 32 x 8
    for (int k = 0; k < 32; k += 8) {
        int r = r0 + ty + k, c = c0 + tx;
        if (r < R && c < C) tile[ty + k][tx] = s[(ll)r * srcR + c];
    }
    __syncthreads();
    for (int k = 0; k < 32; k += 8) {
        int c = c0 + ty + k, r = r0 + tx;
        if (r < R && c < C) d[(ll)c * dstR + r] = __hip_bfloat16(sign * tile[tx][ty + k]);
    }
}

// ================= small utility kernels =================
__global__ void conv_pad(const float* __restrict__ src, __hip_bfloat16* __restrict__ dst,
                         int R, int Cu, int Cp) {
    ll idx = (ll)blockIdx.x * blockDim.x + threadIdx.x;
    if (idx >= (ll)R * Cp) return;
    int r = (int)(idx / Cp), c = (int)(idx % Cp);
    dst[idx] = (c < Cu) ? __hip_bfloat16(src[(ll)r * Cu + c]) : __hip_bfloat16(0.0f);
}

__global__ void conv_mat(const float* __restrict__ src, __hip_bfloat16* __restrict__ dst,
                         int R, int C, int srcLd) {
    ll idx = (ll)blockIdx.x * blockDim.x + threadIdx.x;
    if (idx >= (ll)R * C) return;
    int r = (int)(idx / C), c = (int)(idx % C);
    dst[idx] = __hip_bfloat16(src[(ll)r * srcLd + c]);
}

__global__ void zero_pad(__hip_bfloat16* __restrict__ dst, ll rows, int ld, int c0, int c1) {
    ll idx = (ll)blockIdx.x * blockDim.x + threadIdx.x;
    int w = c1 - c0;
    if (idx >= rows * w) return;
    ll r = idx / w; int c = c0 + (int)(idx % w);
    dst[r * ld + c] = __hip_bfloat16(0.0f);
}

__global__ void build_dmt(__hip_bfloat16* __restrict__ DmT) {
    int idx = blockIdx.x * blockDim.x + threadIdx.x;
    if (idx >= S2 * 384) return;
    int s = idx / 384, w = idx % 384;
    float v = 0.0f;
    if (w < Ww) {
        int m = s % MMAX;
        float ang = (2.0f * (float)M_PI / (float)Ww) * (float)((w * m) % Ww);
        v = (s < MMAX) ? cosf(ang) : -sinf(ang);
    }
    DmT[idx] = __hip_bfloat16(v);
}

__global__ void build_dinvt(__hip_bfloat16* __restrict__ DinvT) {
    int idx = blockIdx.x * blockDim.x + threadIdx.x;
    if (idx >= Ww * 192) return;
    int w = idx / 192, s = idx % 192;
    float v = 0.0f;
    if (s < S2) {
        int m = s % MMAX;
        float ang = (2.0f * (float)M_PI / (float)Ww) * (float)((w * m) % Ww);
        float scale = (m == 0) ? (1.0f / (float)Ww) : (2.0f / (float)Ww);
        if (s < MMAX) v = scale * cosf(ang);
        else          v = (m == 0) ? 0.0f : -scale * sinf(ang);
    }
    DinvT[idx] = __hip_bfloat16(v);
}

__global__ void build_lf(const float* __restrict__ leg_fwd, __hip_bfloat16* __restrict__ LF) {
    int idx = blockIdx.x * blockDim.x + threadIdx.x;
    if (idx >= S2 * LMAX * 192) return;
    int s = idx / (LMAX * 192);
    int rem = idx % (LMAX * 192);
    int l = rem / 192, h = rem % 192;
    float v = (h < Hh) ? leg_fwd[(ll)(s % MMAX) * LMAX * Hh + (ll)l * Hh + h] : 0.0f;
    LF[idx] = __hip_bfloat16(v);
}

__global__ void build_lit(const float* __restrict__ leg_inv, __hip_bfloat16* __restrict__ LIT) {
    int idx = blockIdx.x * blockDim.x + threadIdx.x;
    if (idx >= MMAX * Hh * 96) return;
    int m = idx / (Hh * 96);
    int rem = idx % (Hh * 96);
    int h = rem / 96, l = rem % 96;
    float v = (l < LMAX) ? leg_inv[(ll)m * LMAX * Hh + (ll)l * Hh + h] : 0.0f;
    LIT[idx] = __hip_bfloat16(v);
}

// ================= host helpers =================
static inline void gemmb(hipStream_t st, const __hip_bfloat16* A, int ldA, ll sAb,
                         const __hip_bfloat16* B, int ldB, ll sBb,
                         void* C, ll sCb, ll sCi, ll sCj,
                         const float* Dd, ll sDb, ll sDi, ll sDj,
                         int M, int N, int K, int nb, int epi) {
    GemmBP p{A, B, Dd, C, sAb, ldA, sBb, ldB, sCb, sCi, sCj, sDb, sDi, sDj, M, N, K, epi};
    dim3 g(CDIV(N, 128), CDIV(M, 128), nb);
    gemm_bf<<<g, dim3(256), 0, st>>>(p);
}

static inline void gemm(hipStream_t st, const float* A, const float* B, float* C, const float* Add,
                        int M, int N, int K, int nb,
                        ll sAb, ll sAi, ll sAk,
                        ll sBb, ll sBk, ll sBj,
                        ll sCb, ll sCi, ll sCj,
                        ll sDb, ll sDi, ll sDj,
                        float alpha, int epi) {
    GemmP p{A, B, Add, C, sAb, sAi, sAk, sBb, sBk, sBj, sCb, sCi, sCj, sDb, sDi, sDj,
            M, N, K, alpha, epi};
    dim3 g(CDIV(N, BN), CDIV(M, BM), nb);
    gemm_f32<<<g, dim3(256), 0, st>>>(p);
}

static inline void tcv(hipStream_t st, const float* src, __hip_bfloat16* dst, int R, int C,
                       ll srcB, ll srcR, ll dstB, ll dstR, int nb, float sign) {
    dim3 g(CDIV(C, 32), CDIV(R, 32), nb);
    transp_cv<<<g, dim3(32, 8), 0, st>>>(src, dst, R, C, srcB, srcR, dstB, dstR, sign);
}

extern "C" void kernel_launch(void* const* d_in, const int* in_sizes, int n_in,
                              void* d_out, int out_size, void* d_ws, size_t ws_size,
                              hipStream_t stream) {
    const float* x        = (const float*)d_in[0];
    const float* enc_w1   = (const float*)d_in[1];
    const float* enc_w2   = (const float*)d_in[2];
    const float* pos      = (const float*)d_in[3];
    const float* leg_fwd  = (const float*)d_in[4];
    const float* leg_inv  = (const float*)d_in[5];
    const float* w_spec_r = (const float*)d_in[6];
    const float* w_spec_i = (const float*)d_in[7];
    const float* w_inner  = (const float*)d_in[8];
    const float* w_mlp1   = (const float*)d_in[9];
    const float* w_mlp2   = (const float*)d_in[10];
    const float* dec_w1   = (const float*)d_in[11];
    const float* dec_w2   = (const float*)d_in[12];
    float* out = (float*)d_out;
    float* wsp = (float*)d_ws;

    // ---------------- workspace map (float offsets) ----------------
    float* pool = wsp;
    __hip_bfloat16* HCB  = (__hip_bfloat16*)(pool + 0);          // [46080][384] bf16
    float*          XF   = pool + 8847360;                        // [46080][182] f32
    __hip_bfloat16* XT   = (__hip_bfloat16*)(pool + 0);          // [182][256][192] bf16
    float*          CF   = pool + 8847360;                        // [182][256][90] f32
    __hip_bfloat16* TCF  = (__hip_bfloat16*)(pool + 4472832);    // [90][91][512] bf16
    __hip_bfloat16* WC   = (__hip_bfloat16*)(pool + 13040640);   // [90][512][512] bf16
    float*          CO   = pool + 0;                              // [90][512][91] f32
    __hip_bfloat16* COT  = (__hip_bfloat16*)(pool + 8847360);    // [91][512][96] bf16
    float*          YT   = pool + 0;                              // [91][512][180] f32
    __hip_bfloat16* YF   = (__hip_bfloat16*)(pool + 8847360);    // [46080][192] bf16
    float*          VF   = pool + 13271040;                       // [256][64800] f32
    __hip_bfloat16* HPB  = (__hip_bfloat16*)(pool + 0);          // [64800][256] bf16
    __hip_bfloat16* V2PB = (__hip_bfloat16*)(pool + 0);          // [64800][256] bf16
    __hip_bfloat16* GT   = (__hip_bfloat16*)(pool + 8294400);    // [64800][512] bf16
    float*          V1   = pool + 0;                              // encoder tmp [256][64800] f32
    __hip_bfloat16* V1PB = (__hip_bfloat16*)(pool + 16588800);   // [64800][256] bf16
    const ll POOLSZ = 29859840;

    ll off = POOLSZ;
    float* HC  = wsp + off; off += 16588800;
    float* HC2 = wsp + off; off += 16588800;
    __hip_bfloat16* DmT   = (__hip_bfloat16*)(wsp + off); off += 34944;    // [182][384]
    __hip_bfloat16* DinvT = (__hip_bfloat16*)(wsp + off); off += 34560;    // [360][192]
    __hip_bfloat16* LF    = (__hip_bfloat16*)(wsp + off); off += 1572480;  // [182][90][192]
    __hip_bfloat16* LIT   = (__hip_bfloat16*)(wsp + off); off += 786240;   // [91][180][96]
    __hip_bfloat16* ENC2B = (__hip_bfloat16*)(wsp + off); off += 32768;    // [256][256]
    __hip_bfloat16* WINB  = (__hip_bfloat16*)(wsp + off); off += 32768;    // [256][256]
    __hip_bfloat16* WM1B  = (__hip_bfloat16*)(wsp + off); off += 65536;    // [512][256]
    __hip_bfloat16* WM2B  = (__hip_bfloat16*)(wsp + off); off += 65536;    // [256][512]
    __hip_bfloat16* DW1B  = (__hip_bfloat16*)(wsp + off); off += 32768;    // [256][256]
    __hip_bfloat16* DW2B  = (__hip_bfloat16*)(wsp + off); off += 256;      // [2][256]

    if ((size_t)(off * 4) > ws_size) {
        fprintf(stderr, "kernel_launch: ws too small: need %lld bytes, have %zu\n",
                off * 4, ws_size);
        return;
    }

    const ll EE = (ll)Ech * Ech;

    // ---------------- setup ----------------
    build_dmt  <<<CDIV(S2 * 384, 256), 256, 0, stream>>>(DmT);
    build_dinvt<<<CDIV(Ww * 192, 256), 256, 0, stream>>>(DinvT);
    build_lf   <<<CDIV(S2 * LMAX * 192, 256), 256, 0, stream>>>(leg_fwd, LF);
    build_lit  <<<CDIV(MMAX * Hh * 96, 256), 256, 0, stream>>>(leg_inv, LIT);
    conv_mat<<<CDIV(256 * 256, 256), 256, 0, stream>>>(enc_w2, ENC2B, 256, 256, 256);
    conv_mat<<<CDIV(256 * 256, 256), 256, 0, stream>>>(dec_w1, DW1B, 256, 256, Ech + CIN);
    conv_mat<<<CDIV(2 * 256, 256), 256, 0, stream>>>(dec_w2, DW2B, 2, 256, 256);

    // ---------------- encoder ----------------
    gemm(stream, enc_w1, x, V1, nullptr, Ech, NPIX, CIN, 1,
         0, CIN, 1,  0, NPIX, 1,  0, NPIX, 1,  0, 0, 0,  1.0f, 2);
    tcv(stream, V1, V1PB, 256, NPIX, 0, NPIX, 0, 256, 1, 1.0f);
    gemmb(stream, ENC2B, 256, 0, V1PB, 256, 0, HC, 0, NPIX, 1,
          pos, 0, NPIX, 1, 256, NPIX, 256, 1, 1);

    float* curH = HC;
    float* curN = HC2;

    for (int l = 0; l < NLAYERS; ++l) {
        const float* wr_l = w_spec_r + (ll)l * EE * LMAX;
        const float* wi_l = w_spec_i + (ll)l * EE * LMAX;

        conv_mat<<<CDIV(256 * 256, 256), 256, 0, stream>>>(w_inner + (ll)l * EE, WINB, 256, 256, 256);
        conv_mat<<<CDIV(512 * 256, 256), 256, 0, stream>>>(w_mlp1 + (ll)l * HIDD * Ech, WM1B, 512, 256, 256);
        conv_mat<<<CDIV(256 * 512, 256), 256, 0, stream>>>(w_mlp2 + (ll)l * Ech * HIDD, WM2B, 256, 512, 512);

        // 1. HCB = pad(HC) bf16  [46080][384]
        conv_pad<<<CDIV(46080LL * 384, 256), 256, 0, stream>>>(curH, HCB, CHROWS, Ww, 384);
        // 2. rfft: XF[(ch)][s] = HCB @ DmT^T   M=46080 N=182 K=384
        gemmb(stream, HCB, 384, 0, DmT, 384, 0, XF, 0, 182, 1,
              nullptr, 0, 0, 0, CHROWS, S2, 384, 1, 0);
        // 3. XT[s][c][h] (bf16, h padded to 192)
        zero_pad<<<CDIV(46592LL * 12, 256), 256, 0, stream>>>(XT, 46592LL, 192, 180, 192);
        tcv(stream, XF, XT, Hh, S2, (ll)Hh * S2, S2, 192, 49152, 256, 1.0f);
        // 4. Legendre fwd: CF[s][c][l] : z=182, M=256 N=90 K=192
        gemmb(stream, XT, 192, 49152, LF, 192, 17280, CF, 23040, 90, 1,
              nullptr, 0, 0, 0, 256, LMAX, 192, 182, 0);
        // 5. TCF[l][m][(p,c)] bf16
        for (int pp = 0; pp < 2; ++pp)
            tcv(stream, CF + (ll)pp * 2096640, TCF + (ll)pp * 256, 256, LMAX,
                23040, LMAX, 512, 46592, MMAX, 1.0f);
        // 6. WC[l][o'][cp] = [[Wr, -Wi],[Wi, Wr]] bf16
        tcv(stream, wr_l, WC,                256, LMAX, 23040, LMAX, 512, 262144, 256,  1.0f);
        tcv(stream, wi_l, WC + 256,          256, LMAX, 23040, LMAX, 512, 262144, 256, -1.0f);
        tcv(stream, wi_l, WC + 131072,       256, LMAX, 23040, LMAX, 512, 262144, 256,  1.0f);
        tcv(stream, wr_l, WC + 131072 + 256, 256, LMAX, 23040, LMAX, 512, 262144, 256,  1.0f);
        // 7. spectral filter: CO[l][o'][m] : z=90, M=512 N=91 K=512
        gemmb(stream, WC, 512, 262144, TCF, 512, 46592, CO, 46592, 91, 1,
              nullptr, 0, 0, 0, 512, MMAX, 512, LMAX, 0);
        // 8. COT[m][o'][l] bf16 (l padded to 96)
        zero_pad<<<CDIV(46592LL * 6, 256), 256, 0, stream>>>(COT, 46592LL, 96, 90, 96);
        tcv(stream, CO, COT, LMAX, MMAX, 91, 46592, 96, 49152, 512, 1.0f);
        // 9. Legendre inv: YT[m][o'][h] : z=91, M=512 N=180 K=96
        gemmb(stream, COT, 96, 49152, LIT, 96, 17280, YT, 92160, 180, 1,
              nullptr, 0, 0, 0, 512, Hh, 96, MMAX, 0);
        // 10. YF[(oh)][s] bf16 (s padded to 192)
        zero_pad<<<CDIV(46080LL * 10, 256), 256, 0, stream>>>(YF, 46080LL, 192, 182, 192);
        for (int pp = 0; pp < 2; ++pp)
            tcv(stream, YT + (ll)pp * 46080, YF + (ll)pp * 91, MMAX, CHROWS,
                0, 92160, 0, 192, 1, 1.0f);
        // 11. irfft: VF[c][(hw)] = YF @ DinvT^T : M=46080 N=360 K=192
        gemmb(stream, YF, 192, 0, DinvT, 192, 0, VF, 0, 360, 1,
              nullptr, 0, 0, 0, CHROWS, Ww, 192, 1, 0);
        // 12. HPB = HC^T bf16
        tcv(stream, curH, HPB, 256, NPIX, 0, NPIX, 0, 256, 1, 1.0f);
        // 13. inner skip: VF = w_inner@h + VF
        gemmb(stream, WINB, 256, 0, HPB, 256, 0, VF, 0, NPIX, 1,
              VF, 0, NPIX, 1, 256, NPIX, 256, 1, 1);
        // 14. V2PB = VF^T bf16
        tcv(stream, VF, V2PB, 256, NPIX, 0, NPIX, 0, 256, 1, 1.0f);
        // 15. mlp1: GT[(hw)][hid] = gelu(V2PB @ WM1B^T), bf16 : M=64800 N=512 K=256
        gemmb(stream, V2PB, 256, 0, WM1B, 256, 0, GT, 0, 512, 1,
              nullptr, 0, 0, 0, NPIX, HIDD, 256, 1, 6);
        // 16. mlp2 + residual: M=256 N=64800 K=512
        gemmb(stream, WM2B, 512, 0, GT, 512, 0, curN, 0, NPIX, 1,
              curH, 0, NPIX, 1, 256, NPIX, 512, 1, 1);

        float* tmp = curH; curH = curN; curN = tmp;
    }

    // ---------------- decoder ----------------
    __hip_bfloat16* HPBd = (__hip_bfloat16*)(pool + 0);
    float* T2 = VF;
    tcv(stream, curH, HPBd, 256, NPIX, 0, NPIX, 0, 256, 1, 1.0f);
    gemmb(stream, DW1B, 256, 0, HPBd, 256, 0, T2, 0, NPIX, 1,
          nullptr, 0, 0, 0, 256, NPIX, 256, 1, 0);
    gemm(stream, dec_w1 + Ech, x, T2, T2, Ech, NPIX, CIN, 1,
         0, Ech + CIN, 1,  0, NPIX, 1,  0, NPIX, 1,  0, NPIX, 1,  1.0f, 3);
    __hip_bfloat16* T2PB = (__hip_bfloat16*)(pool + 0);
    tcv(stream, T2, T2PB, 256, NPIX, 0, NPIX, 0, 256, 1, 1.0f);
    gemmb(stream, T2PB, 256, 0, DW2B, 256, 0, out, 0, 1, NPIX,
          nullptr, 0, 0, 0, NPIX, COUTC, 256, 1, 0);
}